// Round 1
// baseline (353.535 us; speedup 1.0000x reference)
//
#include <hip/hip_runtime.h>
#include <hip/hip_bf16.h>

// out = conv3x3(upsample2x(x), ternary(W)) + bias
// Decomposed per output parity (pa,pb) into 2x2 convs on x with effective
// ternary-sum weights (exact in bf16). GEMM via MFMA 16x16x32 bf16.

using bf16x8 = __attribute__((ext_vector_type(8))) short;
using f32x4  = __attribute__((ext_vector_type(4))) float;

static __device__ __forceinline__ unsigned short f2bf(float f) {
  union { float f; unsigned u; } v; v.f = f;
  unsigned r = v.u + 0x7fffu + ((v.u >> 16) & 1u);
  return (unsigned short)(r >> 16);
}

// ---------------- prep weights: quantize + build 16 effective 256x256 mats ----
// wq layout: [(pa*2+pb)*4 + (dh*2+dw)][co][ci]  bf16
__global__ void prep_w_kernel(const float* __restrict__ w,
                              unsigned short* __restrict__ wq) {
  int t = blockIdx.x * 256 + threadIdx.x;   // 65536 threads: one (co,ci) each
  int co = t >> 8, ci = t & 255;
  const float* wp = w + (size_t)(co * 256 + ci) * 9;
  float q[3][3];
#pragma unroll
  for (int kh = 0; kh < 3; ++kh)
#pragma unroll
    for (int kw = 0; kw < 3; ++kw) {
      float x = wp[kh * 3 + kw];
      q[kh][kw] = (x > 0.001f) ? 1.0f : ((x < -0.001f) ? -1.0f : 0.0f);
    }
#pragma unroll
  for (int pa = 0; pa < 2; ++pa)
#pragma unroll
    for (int pb = 0; pb < 2; ++pb)
#pragma unroll
      for (int dh = 0; dh < 2; ++dh)
#pragma unroll
        for (int dw = 0; dw < 2; ++dw) {
          int h0 = dh * (1 + pa), h1 = dh ? 3 : (1 + pa);
          int w0 = dw * (1 + pb), w1 = dw ? 3 : (1 + pb);
          float s = 0.f;
          for (int kh = h0; kh < h1; ++kh)
            for (int kw = w0; kw < w1; ++kw) s += q[kh][kw];
          int par = pa * 2 + pb, tap = dh * 2 + dw;
          wq[((size_t)((par * 4 + tap) * 256 + co)) * 256 + ci] = f2bf(s);
        }
}

// ---------------- transpose x (fp32 NCHW) -> xT bf16 [b][h][w][ci] -----------
__global__ void xpose_kernel(const float* __restrict__ x,
                             unsigned short* __restrict__ xT) {
  __shared__ __align__(16) unsigned short tile[64][72];
  int idx = blockIdx.x;                 // 16*64*4 blocks
  int cb = idx & 3, h = (idx >> 2) & 63, b = idx >> 8;
  int t = threadIdx.x;
  int ci_l = t >> 2, wseg = (t & 3) * 16;
  const float* src = x + ((size_t)((b * 256 + cb * 64 + ci_l) * 64 + h) * 64 + wseg);
#pragma unroll
  for (int j = 0; j < 16; ++j) tile[ci_l][wseg + j] = f2bf(src[j]);
  __syncthreads();
  int w_l = t >> 2, seg = t & 3;
  unsigned short* dst = xT + ((size_t)((b * 64 + h) * 64 + w_l) * 256 + cb * 64 + seg * 16);
  bf16x8 o0, o1;
#pragma unroll
  for (int j = 0; j < 8; ++j) o0[j] = (short)tile[seg * 16 + j][w_l];
#pragma unroll
  for (int j = 0; j < 8; ++j) o1[j] = (short)tile[seg * 16 + 8 + j][w_l];
  *(bf16x8*)dst = o0;
  *(bf16x8*)(dst + 8) = o1;
}

// ---------------- main conv GEMM -------------------------------------------
// Block: 256 thr (4 waves 2x2), tile 64co x 64w, both pb parities folded.
// K loop: pb(2) x tap(4) x ci-chunk(4, BK=64).
__launch_bounds__(256, 2)
__global__ void conv_kernel(const unsigned short* __restrict__ xT,
                            const unsigned short* __restrict__ wq,
                            const float* __restrict__ bias,
                            float* __restrict__ out) {
  __shared__ __align__(16) unsigned short As[64][72];
  __shared__ __align__(16) unsigned short Bs[64][72];
  int idx = blockIdx.x;
  int pix = idx & 1023; int bb = pix >> 6; int h = pix & 63;
  int co_t = (idx >> 10) & 3; int pa = (idx >> 12) & 1;
  int t = threadIdx.x;
  int lane = t & 63, wid = t >> 6;
  int wm = wid >> 1, wn = wid & 1;
  int lr = lane & 15;
  int lk = (lane >> 4) * 8;

  f32x4 acc[2][2][2];   // [pb][fm][fn]
#pragma unroll
  for (int p = 0; p < 2; ++p)
#pragma unroll
    for (int i = 0; i < 2; ++i)
#pragma unroll
      for (int j = 0; j < 2; ++j)
        acc[p][i][j] = (f32x4){0.f, 0.f, 0.f, 0.f};

  int a_row = t >> 3;          // 0..31 (two chunks: a_row, a_row+32)
  int a_col = (t & 7) * 8;
  int b_wr = t >> 2;           // 0..63 (w row of B tile)
  int b_ci = (t & 3) * 16;     // ci segment

#pragma unroll
  for (int pb = 0; pb < 2; ++pb) {
#pragma unroll
    for (int tap = 0; tap < 4; ++tap) {
      int dh = tap >> 1, dw = tap & 1;
      int hx = h - 1 + pa + dh;
      if (hx < 0 || hx > 63) continue;      // block-uniform skip (zero pad)
      int sft = pb - 1 + dw;                // column shift in {-1,0,1}
      const unsigned short* wsrc =
          wq + (size_t)(((pa * 2 + pb) * 4 + tap) * 256 + co_t * 64) * 256;
      const unsigned short* xsrc = xT + (size_t)((bb * 64 + hx) * 64) * 256;
      int wx = b_wr + sft;
      bool wok = (wx >= 0) && (wx < 64);
      const unsigned short* bp = xsrc + (size_t)wx * 256 + b_ci;
      for (int cik = 0; cik < 4; ++cik) {
        int ci0 = cik * 64;
        __syncthreads();
        // stage A (64x64 bf16), 2x16B per thread
        *(bf16x8*)&As[a_row][a_col] =
            *(const bf16x8*)(wsrc + (size_t)a_row * 256 + ci0 + a_col);
        *(bf16x8*)&As[a_row + 32][a_col] =
            *(const bf16x8*)(wsrc + (size_t)(a_row + 32) * 256 + ci0 + a_col);
        // stage B (64w x 64ci bf16), shifted/zero-padded, 2x16B per thread
        bf16x8 lo = {0, 0, 0, 0, 0, 0, 0, 0}, hi = {0, 0, 0, 0, 0, 0, 0, 0};
        if (wok) {
          lo = *(const bf16x8*)(bp + ci0);
          hi = *(const bf16x8*)(bp + ci0 + 8);
        }
        *(bf16x8*)&Bs[b_wr][b_ci] = lo;
        *(bf16x8*)&Bs[b_wr][b_ci + 8] = hi;
        __syncthreads();
#pragma unroll
        for (int kq = 0; kq < 2; ++kq) {
          int kc = kq * 32 + lk;
          bf16x8 a0 = *(const bf16x8*)&As[wm * 32 + lr][kc];
          bf16x8 a1 = *(const bf16x8*)&As[wm * 32 + 16 + lr][kc];
          bf16x8 b0 = *(const bf16x8*)&Bs[wn * 32 + lr][kc];
          bf16x8 b1 = *(const bf16x8*)&Bs[wn * 32 + 16 + lr][kc];
          acc[pb][0][0] = __builtin_amdgcn_mfma_f32_16x16x32_bf16(a0, b0, acc[pb][0][0], 0, 0, 0);
          acc[pb][0][1] = __builtin_amdgcn_mfma_f32_16x16x32_bf16(a0, b1, acc[pb][0][1], 0, 0, 0);
          acc[pb][1][0] = __builtin_amdgcn_mfma_f32_16x16x32_bf16(a1, b0, acc[pb][1][0], 0, 0, 0);
          acc[pb][1][1] = __builtin_amdgcn_mfma_f32_16x16x32_bf16(a1, b1, acc[pb][1][1], 0, 0, 0);
        }
      }
    }
  }

  // epilogue: interleave pb parities -> coalesced float2 stores
  int oh = 2 * h + pa;
#pragma unroll
  for (int fm = 0; fm < 2; ++fm) {
    int co_b = co_t * 64 + wm * 32 + fm * 16 + (lane >> 4) * 4;
#pragma unroll
    for (int i = 0; i < 4; ++i) {
      int co = co_b + i;
      float bi = bias[co];
      float* orow = out + ((size_t)(bb * 256 + co) * 128 + oh) * 128;
#pragma unroll
      for (int fn = 0; fn < 2; ++fn) {
        int ww = wn * 32 + fn * 16 + lr;
        float2 v = make_float2(acc[0][fm][fn][i] + bi, acc[1][fm][fn][i] + bi);
        *(float2*)(orow + 2 * ww) = v;
      }
    }
  }
}

// ---------------- fallback (ws too small): naive direct conv ----------------
__global__ void fallback_kernel(const float* __restrict__ x,
                                const float* __restrict__ w,
                                const float* __restrict__ bias,
                                float* __restrict__ out, long total) {
  long i = (long)blockIdx.x * 256 + threadIdx.x;
  if (i >= total) return;
  int ow = i & 127; int oh = (int)((i >> 7) & 127);
  int co = (int)((i >> 14) & 255); int bb = (int)(i >> 22);
  float s = bias[co];
  for (int ci = 0; ci < 256; ++ci) {
    for (int kh = 0; kh < 3; ++kh) {
      int r = oh - 1 + kh;
      if (r < 0 || r > 127) continue;
      for (int kw = 0; kw < 3; ++kw) {
        int c = ow - 1 + kw;
        if (c < 0 || c > 127) continue;
        float wv = w[((co * 256 + ci) * 3 + kh) * 3 + kw];
        float q = (wv > 0.001f) ? 1.f : ((wv < -0.001f) ? -1.f : 0.f);
        s += q * x[((size_t)(bb * 256 + ci) * 64 + (r >> 1)) * 64 + (c >> 1)];
      }
    }
  }
  out[i] = s;
}

extern "C" void kernel_launch(void* const* d_in, const int* in_sizes, int n_in,
                              void* d_out, int out_size, void* d_ws, size_t ws_size,
                              hipStream_t stream) {
  const float* x    = (const float*)d_in[0];
  const float* wt   = (const float*)d_in[3];
  const float* bias = (const float*)d_in[4];
  float* out = (float*)d_out;

  size_t need = (size_t)2 * 1024 * 1024 + (size_t)16777216 * 2;
  if (ws_size < need) {
    long total = 67108864;
    fallback_kernel<<<(int)((total + 255) / 256), 256, 0, stream>>>(x, wt, bias, out, total);
    return;
  }
  unsigned short* wq = (unsigned short*)d_ws;
  unsigned short* xT = (unsigned short*)((char*)d_ws + 2 * 1024 * 1024);

  prep_w_kernel<<<256, 256, 0, stream>>>(wt, wq);
  xpose_kernel<<<4096, 256, 0, stream>>>(x, xT);
  conv_kernel<<<8192, 256, 0, stream>>>(xT, wq, bias, out);
}

// Round 2
// 220.487 us; speedup vs baseline: 1.6034x; 1.6034x over previous
//
#include <hip/hip_runtime.h>
#include <hip/hip_bf16.h>

// out = conv3x3(upsample2x(x), ternary(W)) + bias
// Per output parity (pa,pb): 2x2 conv on x with effective ternary-sum weights.
// GEMM via MFMA 16x16x32 bf16. A (weights) read fragment-linear from L2;
// B (x rows) staged via global_load_lds with XOR-swizzle (source-side).

using bf16x8 = __attribute__((ext_vector_type(8))) short;
using f32x4  = __attribute__((ext_vector_type(4))) float;

#define MFMA16(a, b, c) __builtin_amdgcn_mfma_f32_16x16x32_bf16(a, b, c, 0, 0, 0)

static __device__ __forceinline__ unsigned short f2bf(float f) {
  union { float f; unsigned u; } v; v.f = f;
  unsigned r = v.u + 0x7fffu + ((v.u >> 16) & 1u);
  return (unsigned short)(r >> 16);
}

static __device__ __forceinline__ void gload_lds16(const void* g, void* l) {
  __builtin_amdgcn_global_load_lds(
      (const __attribute__((address_space(1))) unsigned int*)g,
      (__attribute__((address_space(3))) unsigned int*)l, 16, 0, 0);
}

// ---- prep weights: quantize + 16 effective 256x256 mats, FRAGMENT-LINEAR ----
// frag layout: [(mat*8 + k32)*16 + co16][lane][8elem]; lane = (co&15) + ((ci>>3)&3)*16
__global__ void prep_w_kernel(const float* __restrict__ w,
                              unsigned short* __restrict__ wqf) {
  int t = blockIdx.x * 256 + threadIdx.x;   // one (co,ci) per thread
  int co = t >> 8, ci = t & 255;
  const float* wp = w + (size_t)(co * 256 + ci) * 9;
  float q[3][3];
#pragma unroll
  for (int kh = 0; kh < 3; ++kh)
#pragma unroll
    for (int kw = 0; kw < 3; ++kw) {
      float x = wp[kh * 3 + kw];
      q[kh][kw] = (x > 0.001f) ? 1.0f : ((x < -0.001f) ? -1.0f : 0.0f);
    }
  int k32 = ci >> 5, co16 = co >> 4;
  int lane = (co & 15) + (((ci >> 3) & 3) << 4);
  int e = ci & 7;
#pragma unroll
  for (int pa = 0; pa < 2; ++pa)
#pragma unroll
    for (int pb = 0; pb < 2; ++pb)
#pragma unroll
      for (int dh = 0; dh < 2; ++dh)
#pragma unroll
        for (int dw = 0; dw < 2; ++dw) {
          int h0 = dh * (1 + pa), h1 = dh ? 3 : (1 + pa);
          int w0 = dw * (1 + pb), w1 = dw ? 3 : (1 + pb);
          float s = 0.f;
          for (int kh = h0; kh < h1; ++kh)
            for (int kw = w0; kw < w1; ++kw) s += q[kh][kw];
          int mat = (pa * 2 + pb) * 4 + dh * 2 + dw;
          wqf[((size_t)((mat * 8 + k32) * 16 + co16) * 64 + lane) * 8 + e] = f2bf(s);
        }
}

// ---- transpose x (fp32 NCHW) -> xT bf16 [b][h][w][ci] ----------------------
__global__ void xpose_kernel(const float* __restrict__ x,
                             unsigned short* __restrict__ xT) {
  __shared__ __align__(16) unsigned short tile[64][72];
  int idx = blockIdx.x;                 // 16*64*4 blocks
  int cb = idx & 3, h = (idx >> 2) & 63, b = idx >> 8;
  int t = threadIdx.x;
  int ci_l = t >> 2, wseg = (t & 3) * 16;
  const float* src = x + ((size_t)((b * 256 + cb * 64 + ci_l) * 64 + h) * 64 + wseg);
#pragma unroll
  for (int j = 0; j < 16; ++j) tile[ci_l][wseg + j] = f2bf(src[j]);
  __syncthreads();
  int w_l = t >> 2, seg = t & 3;
  unsigned short* dst = xT + ((size_t)((b * 64 + h) * 64 + w_l) * 256 + cb * 64 + seg * 16);
  bf16x8 o0, o1;
#pragma unroll
  for (int j = 0; j < 8; ++j) o0[j] = (short)tile[seg * 16 + j][w_l];
#pragma unroll
  for (int j = 0; j < 8; ++j) o1[j] = (short)tile[seg * 16 + 8 + j][w_l];
  *(bf16x8*)dst = o0;
  *(bf16x8*)(dst + 8) = o1;
}

// ---- main conv GEMM --------------------------------------------------------
// Block: 512 thr (8 waves, 4 co-chunks x 2 w-halves). Covers one (pa,bb,h):
// all 256 co x 128 ow. Loop (dh,cik): stage Bs[66][64] once, 4 taps read it
// at shifts {-1,0,0,1}. 64 MFMA / 12 ds_read / 2 barriers per wave per stage.
__launch_bounds__(512, 4)
__global__ void conv_kernel(const unsigned short* __restrict__ xT,
                            const unsigned short* __restrict__ wqf,
                            const float* __restrict__ bias,
                            float* __restrict__ out) {
  __shared__ __align__(16) unsigned short Bs[66 * 64];   // byte = col*128 + seg*16

  int bid = blockIdx.x;
  int idx = (bid & 7) * 256 + (bid >> 3);   // bijective XCD swizzle (2048%8==0)
  int pa = idx & 1;
  int h  = (idx >> 1) & 63;
  int bb = idx >> 7;

  int t = threadIdx.x;
  int lane = t & 63, wid = t >> 6;
  int wm = wid >> 1, wn = wid & 1;          // co chunk (64), w half (32)
  int lr = lane & 15, l4 = lane >> 4;

  f32x4 acc[2][4][2];                       // [pb][fm][fn]
#pragma unroll
  for (int p = 0; p < 2; ++p)
#pragma unroll
    for (int m = 0; m < 4; ++m)
#pragma unroll
      for (int n = 0; n < 2; ++n) acc[p][m][n] = (f32x4){0.f, 0.f, 0.f, 0.f};

  // boundary cols 0 and 65 are permanently zero (never re-staged)
  if (t < 32) ((float*)Bs)[t] = 0.f;
  else if (t < 64) ((float*)Bs)[2080 + (t - 32)] = 0.f;

  // staging: thread t covers (col = 1 + t/8, phys seg = t%8); source carries
  // the inverse swizzle so swizzled reads return logical data (rule #21).
  int colS = 1 + (t >> 3);
  int segL = (t & 7) ^ (colS & 7);
  const unsigned short* gsrc0 =
      xT + (((size_t)bb * 64) * 64 + (colS - 1)) * 256 + segL * 8;
  unsigned short* ldst = Bs + wid * 512 + 64;   // bytes: wid*1024 + 128 (wave-uniform)

#pragma unroll
  for (int dh = 0; dh < 2; ++dh) {
    int hx = h - 1 + pa + dh;
    if (hx < 0 || hx > 63) continue;            // block-uniform (zero pad row)
    const unsigned short* grow = gsrc0 + (size_t)hx * (64 * 256);
#pragma unroll
    for (int cik = 0; cik < 4; ++cik) {
      __syncthreads();                          // prev compute done
      gload_lds16(grow + cik * 64, ldst);       // 8KB: cols 1..64, ci chunk
      __syncthreads();                          // vmcnt(0) drain -> data ready
#pragma unroll
      for (int kq = 0; kq < 2; ++kq) {
        bf16x8 bfr[3][2];                       // [shift+1][fn]
#pragma unroll
        for (int s3 = 0; s3 < 3; ++s3)
#pragma unroll
          for (int fn = 0; fn < 2; ++fn) {
            int col = wn * 32 + fn * 16 + lr + s3;       // 0..65
            int seg = (kq * 4 + l4) ^ (col & 7);         // XOR de-swizzle
            bfr[s3][fn] = *(const bf16x8*)((const char*)Bs + col * 128 + seg * 16);
          }
#pragma unroll
        for (int pb = 0; pb < 2; ++pb)
#pragma unroll
          for (int dw = 0; dw < 2; ++dw) {
            int mat = (pa * 2 + pb) * 4 + dh * 2 + dw;
            int s3 = pb + dw;                   // shift+1
#pragma unroll
            for (int fm = 0; fm < 4; ++fm) {
              bf16x8 a = *(const bf16x8*)(wqf +
                  ((size_t)((mat * 8 + cik * 2 + kq) * 16 + wm * 4 + fm)) * 512 +
                  lane * 8);                    // coalesced 1KB/wave from L2
              acc[pb][fm][0] = MFMA16(a, bfr[s3][0], acc[pb][fm][0]);
              acc[pb][fm][1] = MFMA16(a, bfr[s3][1], acc[pb][fm][1]);
            }
          }
      }
    }
  }

  // epilogue: pb-interleaved float2 stores (coalesced 128B per 16 lanes)
  int oh = 2 * h + pa;
#pragma unroll
  for (int fm = 0; fm < 4; ++fm) {
    int co0 = wm * 64 + fm * 16 + l4 * 4;
#pragma unroll
    for (int i = 0; i < 4; ++i) {
      float bi = bias[co0 + i];
      float* orow = out + ((size_t)(bb * 256 + co0 + i) * 128 + oh) * 128;
#pragma unroll
      for (int fn = 0; fn < 2; ++fn) {
        int ww = wn * 32 + fn * 16 + lr;
        *(float2*)(orow + 2 * ww) =
            make_float2(acc[0][fm][fn][i] + bi, acc[1][fm][fn][i] + bi);
      }
    }
  }
}

// ---- fallback (ws too small): naive direct conv ----------------------------
__global__ void fallback_kernel(const float* __restrict__ x,
                                const float* __restrict__ w,
                                const float* __restrict__ bias,
                                float* __restrict__ out, long total) {
  long i = (long)blockIdx.x * 256 + threadIdx.x;
  if (i >= total) return;
  int ow = i & 127; int oh = (int)((i >> 7) & 127);
  int co = (int)((i >> 14) & 255); int bb = (int)(i >> 22);
  float s = bias[co];
  for (int ci = 0; ci < 256; ++ci) {
    for (int kh = 0; kh < 3; ++kh) {
      int r = oh - 1 + kh;
      if (r < 0 || r > 127) continue;
      for (int kw = 0; kw < 3; ++kw) {
        int c = ow - 1 + kw;
        if (c < 0 || c > 127) continue;
        float wv = w[((co * 256 + ci) * 3 + kh) * 3 + kw];
        float q = (wv > 0.001f) ? 1.f : ((wv < -0.001f) ? -1.f : 0.f);
        s += q * x[((size_t)(bb * 256 + ci) * 64 + (r >> 1)) * 64 + (c >> 1)];
      }
    }
  }
  out[i] = s;
}

extern "C" void kernel_launch(void* const* d_in, const int* in_sizes, int n_in,
                              void* d_out, int out_size, void* d_ws, size_t ws_size,
                              hipStream_t stream) {
  const float* x    = (const float*)d_in[0];
  const float* wt   = (const float*)d_in[3];
  const float* bias = (const float*)d_in[4];
  float* out = (float*)d_out;

  size_t need = (size_t)2 * 1024 * 1024 + (size_t)16777216 * 2;
  if (ws_size < need) {
    long total = 67108864;
    fallback_kernel<<<(int)((total + 255) / 256), 256, 0, stream>>>(x, wt, bias, out, total);
    return;
  }
  unsigned short* wqf = (unsigned short*)d_ws;
  unsigned short* xT  = (unsigned short*)((char*)d_ws + 2 * 1024 * 1024);

  prep_w_kernel<<<256, 256, 0, stream>>>(wt, wqf);
  xpose_kernel<<<4096, 256, 0, stream>>>(x, xT);
  conv_kernel<<<2048, 512, 0, stream>>>(xT, wqf, bias, out);
}

// Round 3
// 164.217 us; speedup vs baseline: 2.1528x; 1.3427x over previous
//
#include <hip/hip_runtime.h>
#include <hip/hip_bf16.h>

// out = conv3x3(upsample2x(x), ternary(W)) + bias
// Per output parity (pa,pb): 2x2 conv on x with effective ternary-sum weights.
// GEMM via MFMA 16x16x32 bf16. Weights streamed fragment-linear from L2;
// x rows staged once per block into 64KB LDS (XOR-swizzled), ONE barrier.

using bf16x8 = __attribute__((ext_vector_type(8))) short;
using f32x4  = __attribute__((ext_vector_type(4))) float;

#define MFMA16(a, b, c) __builtin_amdgcn_mfma_f32_16x16x32_bf16(a, b, c, 0, 0, 0)

static __device__ __forceinline__ unsigned short f2bf(float f) {
  union { float f; unsigned u; } v; v.f = f;
  unsigned r = v.u + 0x7fffu + ((v.u >> 16) & 1u);
  return (unsigned short)(r >> 16);
}

static __device__ __forceinline__ void gload_lds16(const void* g, void* l) {
  __builtin_amdgcn_global_load_lds(
      (const __attribute__((address_space(1))) unsigned int*)g,
      (__attribute__((address_space(3))) unsigned int*)l, 16, 0, 0);
}

// ---- prep weights: quantize + 16 effective 256x256 mats, per-wave linear ----
// idx = (((pa*2+dh)*8 + wm)*64 + frag)*512 + lane*8 + e
// frag = (((cik*2+kq)*2 + pb)*2 + dw)*2 + fm ; co16 = wm*2+fm ; k32 = cik*2+kq
// lane = (co&15) | (((ci>>3)&3)<<4) ; e = ci&7
__global__ void prep_w_kernel(const float* __restrict__ w,
                              unsigned short* __restrict__ wqf) {
  int t = blockIdx.x * 256 + threadIdx.x;   // one (co,ci) per thread
  int co = t >> 8, ci = t & 255;
  const float* wp = w + (size_t)(co * 256 + ci) * 9;
  float q[3][3];
#pragma unroll
  for (int kh = 0; kh < 3; ++kh)
#pragma unroll
    for (int kw = 0; kw < 3; ++kw) {
      float x = wp[kh * 3 + kw];
      q[kh][kw] = (x > 0.001f) ? 1.0f : ((x < -0.001f) ? -1.0f : 0.0f);
    }
  int co16 = co >> 4, wm = co16 >> 1, fm = co16 & 1;
  int k32 = ci >> 5, cik = k32 >> 1, kq = k32 & 1;
  int lane = (co & 15) | (((ci >> 3) & 3) << 4);
  int e = ci & 7;
#pragma unroll
  for (int pa = 0; pa < 2; ++pa)
#pragma unroll
    for (int pb = 0; pb < 2; ++pb)
#pragma unroll
      for (int dh = 0; dh < 2; ++dh)
#pragma unroll
        for (int dw = 0; dw < 2; ++dw) {
          int h0 = dh * (1 + pa), h1 = dh ? 3 : (1 + pa);
          int w0 = dw * (1 + pb), w1 = dw ? 3 : (1 + pb);
          float s = 0.f;
          for (int kh = h0; kh < h1; ++kh)
            for (int kw = w0; kw < w1; ++kw) s += q[kh][kw];
          int frag = (((cik * 2 + kq) * 2 + pb) * 2 + dw) * 2 + fm;
          size_t idx =
              ((size_t)(((pa * 2 + dh) * 8 + wm) * 64 + frag)) * 512 + lane * 8 + e;
          wqf[idx] = f2bf(s);
        }
}

// ---- transpose x (fp32 NCHW) -> xT bf16 [b][h][w][ci] ----------------------
__global__ void xpose_kernel(const float* __restrict__ x,
                             unsigned short* __restrict__ xT) {
  __shared__ __align__(16) unsigned short tile[64][72];
  int idx = blockIdx.x;                 // 16*64*4 blocks
  int cb = idx & 3, h = (idx >> 2) & 63, b = idx >> 8;
  int t = threadIdx.x;
  int ci_l = t >> 2, wseg = (t & 3) * 16;
  const float* src = x + ((size_t)((b * 256 + cb * 64 + ci_l) * 64 + h) * 64 + wseg);
#pragma unroll
  for (int j = 0; j < 16; ++j) tile[ci_l][wseg + j] = f2bf(src[j]);
  __syncthreads();
  int w_l = t >> 2, seg = t & 3;
  unsigned short* dst = xT + ((size_t)((b * 64 + h) * 64 + w_l) * 256 + cb * 64 + seg * 16);
  bf16x8 o0, o1;
#pragma unroll
  for (int j = 0; j < 8; ++j) o0[j] = (short)tile[seg * 16 + j][w_l];
#pragma unroll
  for (int j = 0; j < 8; ++j) o1[j] = (short)tile[seg * 16 + 8 + j][w_l];
  *(bf16x8*)dst = o0;
  *(bf16x8*)(dst + 8) = o1;
}

// ---- main conv GEMM --------------------------------------------------------
// Block: 512 thr (8 waves), tile 256co x 128ow (one output row oh=2h+pa).
// Wave: 32co x 64w x 2pb. Stage ALL B (2dh x 4cik x 8KB = 64KB) once ->
// one barrier -> 16 kq-units x 32 MFMA with no further syncs.
__launch_bounds__(512, 4)
__global__ void conv_kernel(const unsigned short* __restrict__ xT,
                            const unsigned short* __restrict__ wqf,
                            const float* __restrict__ bias,
                            float* __restrict__ out) {
  // chunk (dh*4+cik): [64 cols][8 seg][16B] = 8192 B; byte = col*128 + seg*16
  __shared__ __align__(16) unsigned char Bs[8 * 8192];   // 64 KB exactly

  int bid = blockIdx.x;
  int idx = (bid & 7) * 256 + (bid >> 3);   // bijective XCD swizzle (2048%8==0)
  int pa = idx & 1;
  int h  = (idx >> 1) & 63;
  int bb = idx >> 7;

  int t = threadIdx.x;
  int lane = t & 63, wid = t >> 6;
  int lr = lane & 15, l4 = lane >> 4;

  bool dhok[2];
  dhok[0] = (h - 1 + pa) >= 0;
  dhok[1] = (h + pa) <= 63;

  // ---- stage everything (source-side inverse swizzle, rule #21) ----
  {
    int colS = t >> 3;                    // w col 0..63
    int segL = (t & 7) ^ (colS & 7);
    const unsigned short* g0 =
        xT + (((size_t)bb * 64) * 64 + colS) * 256 + segL * 8;
#pragma unroll
    for (int dh = 0; dh < 2; ++dh) {
      if (!dhok[dh]) continue;
      int hx = h - 1 + pa + dh;
      const unsigned short* grow = g0 + (size_t)hx * (64 * 256);
#pragma unroll
      for (int cik = 0; cik < 4; ++cik) {
        gload_lds16(grow + cik * 64,
                    Bs + (dh * 4 + cik) * 8192 + wid * 1024);
      }
    }
  }

  f32x4 acc[2][2][4];                     // [pb][fm][fn]
#pragma unroll
  for (int p = 0; p < 2; ++p)
#pragma unroll
    for (int m = 0; m < 2; ++m)
#pragma unroll
      for (int n = 0; n < 4; ++n) acc[p][m][n] = (f32x4){0.f, 0.f, 0.f, 0.f};

  // LDS read offset pieces: addr = chunk + ((fn*16 + lr + s3 - 1)&63)*128 + seg*16
  // seg = (kq*4+l4) ^ ((lr+s3-1)&7)   (fn*16 = 0 mod 8)
  int segoff[2][3];
#pragma unroll
  for (int kq = 0; kq < 2; ++kq)
#pragma unroll
    for (int s3 = 0; s3 < 3; ++s3)
      segoff[kq][s3] = (((kq * 4 + l4) ^ ((lr + s3 - 1) & 7)) << 4);

  const bf16x8 zfr = {0, 0, 0, 0, 0, 0, 0, 0};
  bool edgeLo = (lr == 0);    // s3=0, fn=0 reads w=-1 -> zero
  bool edgeHi = (lr == 15);   // s3=2, fn=3 reads w=64 -> zero

  __syncthreads();            // vmcnt(0)+lgkmcnt drain: all B resident

#pragma unroll
  for (int dh = 0; dh < 2; ++dh) {
    if (!dhok[dh]) continue;
    const unsigned short* awave =
        wqf + ((size_t)((pa * 2 + dh) * 8 + wid)) * 32768 + lane * 8;
    const unsigned char* bch = Bs + dh * 4 * 8192;
#pragma unroll
    for (int cik = 0; cik < 4; ++cik) {
      const unsigned char* bc = bch + cik * 8192;
#pragma unroll
      for (int kq = 0; kq < 2; ++kq) {
        const unsigned short* au = awave + (cik * 2 + kq) * 4096;
        bf16x8 bf[4], a0, a1;
        // ---- s3 = 0 : mat (pb=0,dw=0) ----
#pragma unroll
        for (int fn = 0; fn < 4; ++fn)
          bf[fn] = *(const bf16x8*)(bc + (((fn * 16 + lr - 1) & 63) << 7) + segoff[kq][0]);
        if (edgeLo) bf[0] = zfr;
        a0 = *(const bf16x8*)(au);
        a1 = *(const bf16x8*)(au + 512);
#pragma unroll
        for (int fn = 0; fn < 4; ++fn) {
          acc[0][0][fn] = MFMA16(a0, bf[fn], acc[0][0][fn]);
          acc[0][1][fn] = MFMA16(a1, bf[fn], acc[0][1][fn]);
        }
        // ---- s3 = 1 : mats (0,1) and (1,0) share B ----
#pragma unroll
        for (int fn = 0; fn < 4; ++fn)
          bf[fn] = *(const bf16x8*)(bc + (((fn * 16 + lr) & 63) << 7) + segoff[kq][1]);
        a0 = *(const bf16x8*)(au + 2 * 512);
        a1 = *(const bf16x8*)(au + 3 * 512);
#pragma unroll
        for (int fn = 0; fn < 4; ++fn) {
          acc[0][0][fn] = MFMA16(a0, bf[fn], acc[0][0][fn]);
          acc[0][1][fn] = MFMA16(a1, bf[fn], acc[0][1][fn]);
        }
        a0 = *(const bf16x8*)(au + 4 * 512);
        a1 = *(const bf16x8*)(au + 5 * 512);
#pragma unroll
        for (int fn = 0; fn < 4; ++fn) {
          acc[1][0][fn] = MFMA16(a0, bf[fn], acc[1][0][fn]);
          acc[1][1][fn] = MFMA16(a1, bf[fn], acc[1][1][fn]);
        }
        // ---- s3 = 2 : mat (1,1) ----
#pragma unroll
        for (int fn = 0; fn < 4; ++fn)
          bf[fn] = *(const bf16x8*)(bc + (((fn * 16 + lr + 1) & 63) << 7) + segoff[kq][2]);
        if (edgeHi) bf[3] = zfr;
        a0 = *(const bf16x8*)(au + 6 * 512);
        a1 = *(const bf16x8*)(au + 7 * 512);
#pragma unroll
        for (int fn = 0; fn < 4; ++fn) {
          acc[1][0][fn] = MFMA16(a0, bf[fn], acc[1][0][fn]);
          acc[1][1][fn] = MFMA16(a1, bf[fn], acc[1][1][fn]);
        }
      }
    }
  }

  // ---- epilogue: pb-interleaved float2 stores ----
  int oh = 2 * h + pa;
#pragma unroll
  for (int fm = 0; fm < 2; ++fm) {
    int co0 = wid * 32 + fm * 16 + l4 * 4;
#pragma unroll
    for (int i = 0; i < 4; ++i) {
      float bi = bias[co0 + i];
      float* orow = out + ((size_t)(bb * 256 + co0 + i) * 128 + oh) * 128;
#pragma unroll
      for (int fn = 0; fn < 4; ++fn) {
        int ww = fn * 16 + lr;
        *(float2*)(orow + 2 * ww) =
            make_float2(acc[0][fm][fn][i] + bi, acc[1][fm][fn][i] + bi);
      }
    }
  }
}

// ---- fallback (ws too small): naive direct conv ----------------------------
__global__ void fallback_kernel(const float* __restrict__ x,
                                const float* __restrict__ w,
                                const float* __restrict__ bias,
                                float* __restrict__ out, long total) {
  long i = (long)blockIdx.x * 256 + threadIdx.x;
  if (i >= total) return;
  int ow = i & 127; int oh = (int)((i >> 7) & 127);
  int co = (int)((i >> 14) & 255); int bb = (int)(i >> 22);
  float s = bias[co];
  for (int ci = 0; ci < 256; ++ci) {
    for (int kh = 0; kh < 3; ++kh) {
      int r = oh - 1 + kh;
      if (r < 0 || r > 127) continue;
      for (int kw = 0; kw < 3; ++kw) {
        int c = ow - 1 + kw;
        if (c < 0 || c > 127) continue;
        float wv = w[((co * 256 + ci) * 3 + kh) * 3 + kw];
        float q = (wv > 0.001f) ? 1.f : ((wv < -0.001f) ? -1.f : 0.f);
        s += q * x[((size_t)(bb * 256 + ci) * 64 + (r >> 1)) * 64 + (c >> 1)];
      }
    }
  }
  out[i] = s;
}

extern "C" void kernel_launch(void* const* d_in, const int* in_sizes, int n_in,
                              void* d_out, int out_size, void* d_ws, size_t ws_size,
                              hipStream_t stream) {
  const float* x    = (const float*)d_in[0];
  const float* wt   = (const float*)d_in[3];
  const float* bias = (const float*)d_in[4];
  float* out = (float*)d_out;

  size_t need = (size_t)2 * 1024 * 1024 + (size_t)16777216 * 2;
  if (ws_size < need) {
    long total = 67108864;
    fallback_kernel<<<(int)((total + 255) / 256), 256, 0, stream>>>(x, wt, bias, out, total);
    return;
  }
  unsigned short* wqf = (unsigned short*)d_ws;
  unsigned short* xT  = (unsigned short*)((char*)d_ws + 2 * 1024 * 1024);

  prep_w_kernel<<<256, 256, 0, stream>>>(wt, wqf);
  xpose_kernel<<<4096, 256, 0, stream>>>(x, xT);
  conv_kernel<<<2048, 512, 0, stream>>>(xT, wqf, bias, out);
}